// Round 2
// baseline (2322.486 us; speedup 1.0000x reference)
//
#include <hip/hip_runtime.h>
#include <cstdint>
#include <cstddef>

// Problem: B=64, T=512, I=128, H=256, 4H=1024, C=3. All fp32 in/out.
typedef _Float16 half2_t __attribute__((ext_vector_type(2)));
typedef _Float16 half8_t __attribute__((ext_vector_type(8)));
typedef float f32x4 __attribute__((ext_vector_type(4)));

static __device__ __forceinline__ float fdot2(half2_t a, half2_t b, float c) {
    return __builtin_amdgcn_fdot2(a, b, c, false);
}
static __device__ __forceinline__ half2_t h2(unsigned int u) {
    return __builtin_bit_cast(half2_t, u);
}
static __device__ __forceinline__ float sigm(float x) {
    return 1.f / (1.f + __expf(-x));
}
static __device__ __forceinline__ float tanh_fast(float x) {
    float ax = fabsf(x);
    float e = __expf(2.f * ax);
    float r = 1.f - 2.f / (e + 1.f);
    return copysignf(r, x);
}

// ---------------------------------------------------------------------------
// prep: W_hh (1024x256 fp32) -> f16 chunk layout for the K-split-4 scan.
// chunk c = g*8+u (g=gate block 0..3, u=0..7), plane[c][tid]:
//   tid = w*64 + ks*16 + jl  ->  8 halves of W[g*256 + w*16 + jl][ks*64 + u*8 ..]
// bias = b_ih + b_hh
// ---------------------------------------------------------------------------
__global__ __launch_bounds__(256) void prep_whh(const float* __restrict__ Whh,
                                                const float* __restrict__ bih,
                                                const float* __restrict__ bhh,
                                                uint4* __restrict__ Wp,
                                                float* __restrict__ bias) {
    int n = blockIdx.x * 256 + threadIdx.x;  // 0..32767
    if (n < 1024) bias[n] = bih[n] + bhh[n];
    int c = n >> 10;        // chunk 0..31
    int tid = n & 1023;
    int g = c >> 3, u = c & 7;
    int w = tid >> 6, l = tid & 63;
    int ks = l >> 4, jl = l & 15;
    int row = g * 256 + w * 16 + jl;
    int kb = ks * 64 + u * 8;
    union { uint4 u4; _Float16 h[8]; } cv;
#pragma unroll
    for (int i = 0; i < 8; ++i) cv.h[i] = (_Float16)Whh[row * 256 + kb + i];
    Wp[c * 1024 + tid] = cv.u4;
}

// f32 -> f16, 4 elements/thread
__global__ __launch_bounds__(256) void cvt_f16(const float* __restrict__ in,
                                               _Float16* __restrict__ out, int n4) {
    int i = blockIdx.x * 256 + threadIdx.x;
    if (i < n4) {
        float4 v = ((const float4*)in)[i];
        union { ushort4 u; _Float16 h[4]; } cv;
        cv.h[0] = (_Float16)v.x; cv.h[1] = (_Float16)v.y;
        cv.h[2] = (_Float16)v.z; cv.h[3] = (_Float16)v.w;
        ((ushort4*)out)[i] = cv.u;
    }
}

// ---------------------------------------------------------------------------
// gemm_mfma: C[M][1024] = A[M][K](f16) * W[1024][K](f16)^T + bias, fp32 out.
// ---------------------------------------------------------------------------
__global__ __launch_bounds__(256) void gemm_mfma(const _Float16* __restrict__ A,
                                                 const _Float16* __restrict__ Bw,
                                                 const float* __restrict__ bias,
                                                 float* __restrict__ Cmat, int K) {
    __shared__ _Float16 As[64][72];
    __shared__ _Float16 Bs[64][72];
    const int tid = threadIdx.x;
    const int wave = tid >> 6, lane = tid & 63;
    const int quad = lane >> 4, l16 = lane & 15;
    const int m0 = blockIdx.x * 64, n0 = blockIdx.y * 64;
    const int sr = tid >> 2;
    const int sc = (tid & 3) * 16;

    f32x4 acc[4] = {};

    for (int k0 = 0; k0 < K; k0 += 64) {
        const uint4 a0v = *(const uint4*)(A + (size_t)(m0 + sr) * K + k0 + sc);
        const uint4 a1v = *(const uint4*)(A + (size_t)(m0 + sr) * K + k0 + sc + 8);
        const uint4 b0v = *(const uint4*)(Bw + (size_t)(n0 + sr) * K + k0 + sc);
        const uint4 b1v = *(const uint4*)(Bw + (size_t)(n0 + sr) * K + k0 + sc + 8);
        __syncthreads();
        *(uint4*)&As[sr][sc] = a0v;
        *(uint4*)&As[sr][sc + 8] = a1v;
        *(uint4*)&Bs[sr][sc] = b0v;
        *(uint4*)&Bs[sr][sc + 8] = b1v;
        __syncthreads();
#pragma unroll
        for (int kc = 0; kc < 64; kc += 32) {
            half8_t af = *(const half8_t*)&As[wave * 16 + l16][kc + quad * 8];
#pragma unroll
            for (int nb = 0; nb < 4; ++nb) {
                half8_t bf = *(const half8_t*)&Bs[nb * 16 + l16][kc + quad * 8];
                acc[nb] = __builtin_amdgcn_mfma_f32_16x16x32_f16(af, bf, acc[nb], 0, 0, 0);
            }
        }
    }
#pragma unroll
    for (int nb = 0; nb < 4; ++nb) {
#pragma unroll
        for (int i = 0; i < 4; ++i) {
            int row = m0 + wave * 16 + quad * 4 + i;
            int col = n0 + nb * 16 + l16;
            Cmat[(size_t)row * 1024 + col] = acc[nb][i] + bias[col];
        }
    }
}

// ---------------------------------------------------------------------------
// lstm_scan v7: 64 WGs x 1024 thr (16 waves, 128-VGPR operating point).
// K-split-4 remap: thread (w, ks, jl) computes 4 gate rows {g*256 + w*16 + jl}
// over K-slice [ks*64, ks*64+64). Its h-read is 8 uint4 (vs 32 before):
// LDS return traffic for h drops 4x (512KB -> 128KB per step per CU).
// The 4 K-slice partials of each row live in lanes {l, l^16, l^32, l^48} of
// the SAME wave -> 8 shfl_xor butterfly replaces the actf LDS round-trip.
// After the butterfly every lane holds all 4 gate pre-acts of its unit ->
// per-wave in-register h update (no 256-thread serial phase).
// h double-buffered (576B each, 144B chunk stride so the 4 broadcast groups
// hit disjoint bank quads) -> 1 barrier/step instead of 2.
// Weights: chunks 0..23 in 96 VGPRs, chunks 24..31 (g=3) in 128KB LDS.
// ---------------------------------------------------------------------------
__global__ __attribute__((amdgpu_flat_work_group_size(1024, 1024)))
void lstm_scan(const float* __restrict__ gx,
               const uint4* __restrict__ Wp,
               _Float16* __restrict__ h_out,
               int store_all) {
    const int b = blockIdx.x;
    const int tid = threadIdx.x;
    const int w = tid >> 6;       // wave 0..15
    const int l = tid & 63;
    const int ks = l >> 4;        // K-slice 0..3 (64 h elems each)
    const int jl = l & 15;
    const int j = w * 16 + jl;    // hidden unit 0..255

    __shared__ uint4 wlds[8 * 1024];                                 // 128 KB
    __shared__ _Float16 hbuf[2][288] __attribute__((aligned(16)));   // 2 x 576 B
    __shared__ _Float16 hist[16][256] __attribute__((aligned(16)));  // 8 KB

    // stage weight chunks 24..31 (g=3) into LDS
#pragma unroll
    for (int q = 0; q < 8; ++q) wlds[q * 1024 + tid] = Wp[(24 + q) * 1024 + tid];
    // persistent register weights: chunks 0..23 (g=0..2), 96 VGPRs
    uint4 wreg[24];
#pragma unroll
    for (int u = 0; u < 24; ++u) wreg[u] = Wp[u * 1024 + tid];

    if (tid < 288) hbuf[0][tid] = (_Float16)0.f;
    float c = 0.f;
    // this thread's gx element: row = ks*256 + j (added to acc[ks] pre-reduce)
    const float* gxb = gx + (size_t)b * 512 * 1024 + (size_t)(ks * 256 + j);
    float g_cur = gxb[0];
    __syncthreads();  // wlds + hbuf[0] visible

    for (int t = 0; t < 512; ++t) {
        float g_nxt = 0.f;
        if (t < 511) g_nxt = gxb[(size_t)(t + 1) * 1024];

        // h slice for this K-slice: 8 uint4 at chunk stride 144B
        const char* hp = (const char*)&hbuf[t & 1][0] + ks * 144;
        float a0 = 0.f, a1 = 0.f, a2 = 0.f, a3 = 0.f;
#pragma unroll
        for (int u = 0; u < 8; ++u) {
            const uint4 hv = *(const uint4*)(hp + u * 16);
            const uint4 w0 = wreg[u];
            const uint4 w1 = wreg[8 + u];
            const uint4 w2 = wreg[16 + u];
            const uint4 w3 = wlds[u * 1024 + tid];
            a0 = fdot2(h2(w0.x), h2(hv.x), a0);
            a1 = fdot2(h2(w1.x), h2(hv.x), a1);
            a2 = fdot2(h2(w2.x), h2(hv.x), a2);
            a3 = fdot2(h2(w3.x), h2(hv.x), a3);
            a0 = fdot2(h2(w0.y), h2(hv.y), a0);
            a1 = fdot2(h2(w1.y), h2(hv.y), a1);
            a2 = fdot2(h2(w2.y), h2(hv.y), a2);
            a3 = fdot2(h2(w3.y), h2(hv.y), a3);
            a0 = fdot2(h2(w0.z), h2(hv.z), a0);
            a1 = fdot2(h2(w1.z), h2(hv.z), a1);
            a2 = fdot2(h2(w2.z), h2(hv.z), a2);
            a3 = fdot2(h2(w3.z), h2(hv.z), a3);
            a0 = fdot2(h2(w0.w), h2(hv.w), a0);
            a1 = fdot2(h2(w1.w), h2(hv.w), a1);
            a2 = fdot2(h2(w2.w), h2(hv.w), a2);
            a3 = fdot2(h2(w3.w), h2(hv.w), a3);
        }
        // add gx once per row: lane ks holds gx[ks*256+j] -> goes into acc[ks]
        a0 += (ks == 0) ? g_cur : 0.f;
        a1 += (ks == 1) ? g_cur : 0.f;
        a2 += (ks == 2) ? g_cur : 0.f;
        a3 += (ks == 3) ? g_cur : 0.f;

        // butterfly over the 4 K-slice lanes (commutative adds -> identical
        // values in all 4 lanes; c stays replicated consistently)
        a0 += __shfl_xor(a0, 16);
        a1 += __shfl_xor(a1, 16);
        a2 += __shfl_xor(a2, 16);
        a3 += __shfl_xor(a3, 16);
        a0 += __shfl_xor(a0, 32);
        a1 += __shfl_xor(a1, 32);
        a2 += __shfl_xor(a2, 32);
        a3 += __shfl_xor(a3, 32);

        const float iv = sigm(a0);
        const float fv = sigm(a1);
        const float gv = tanh_fast(a2);
        const float ov = sigm(a3);
        c = fv * c + iv * gv;
        const _Float16 hh = (_Float16)(ov * tanh_fast(c));

        // publish h^(t) into the other buffer (unit j at chunk (j>>6), 144B stride)
        char* wbase = (char*)&hbuf[(t + 1) & 1][0];
        if (ks == 0)
            *(_Float16*)(wbase + (w >> 2) * 144 + (size_t)(((w & 3) * 16 + jl) * 2)) = hh;
        if (store_all && ks == 1) hist[t & 15][j] = hh;
        g_cur = g_nxt;
        __syncthreads();  // h^(t) + hist visible; all reads of h^(t-1) done

        if (store_all && (t & 15) == 15) {
            // flush 16 steps (8 KB) with all 1024 threads (8 B each)
            const uint2 v = ((const uint2*)hist)[tid];
            *(uint2*)(h_out + (size_t)b * 512 * 256 + (size_t)(t - 15) * 256 + tid * 4) = v;
            __syncthreads();  // flush reads done before next hist overwrite
        }
    }
    if (!store_all && tid < 256) {
        // final h lives in hbuf[0] (512 & 1 == 0), 144B-chunk layout
        h_out[(size_t)b * 256 + tid] = hbuf[0][(tid >> 6) * 72 + (tid & 63)];
    }
}

// ---------------------------------------------------------------------------
// fc_softmax: logits = hlast[b,:](f16) @ fc_w^T + fc_b, softmax over 3
// ---------------------------------------------------------------------------
__global__ __launch_bounds__(64) void fc_softmax(const _Float16* __restrict__ hlast,
                                                 const float* __restrict__ fcw,
                                                 const float* __restrict__ fcb,
                                                 float* __restrict__ out) {
    const int b = blockIdx.x;
    const int lane = threadIdx.x;
    const _Float16* h = hlast + (size_t)b * 256;
    float p0 = 0.f, p1 = 0.f, p2 = 0.f;
    for (int k = lane; k < 256; k += 64) {
        float hv = (float)h[k];
        p0 += hv * fcw[k];
        p1 += hv * fcw[256 + k];
        p2 += hv * fcw[512 + k];
    }
#pragma unroll
    for (int off = 32; off > 0; off >>= 1) {
        p0 += __shfl_down(p0, off);
        p1 += __shfl_down(p1, off);
        p2 += __shfl_down(p2, off);
    }
    if (lane == 0) {
        float l0 = p0 + fcb[0], l1 = p1 + fcb[1], l2 = p2 + fcb[2];
        float m = fmaxf(l0, fmaxf(l1, l2));
        float e0 = __expf(l0 - m), e1 = __expf(l1 - m), e2 = __expf(l2 - m);
        float s = 1.f / (e0 + e1 + e2);
        out[b * 3 + 0] = e0 * s;
        out[b * 3 + 1] = e1 * s;
        out[b * 3 + 2] = e2 * s;
    }
}

extern "C" void kernel_launch(void* const* d_in, const int* in_sizes, int n_in,
                              void* d_out, int out_size, void* d_ws, size_t ws_size,
                              hipStream_t stream) {
    const float* x    = (const float*)d_in[0];
    const float* Wih0 = (const float*)d_in[1];
    const float* Whh0 = (const float*)d_in[2];
    const float* bih0 = (const float*)d_in[3];
    const float* bhh0 = (const float*)d_in[4];
    const float* Wih1 = (const float*)d_in[5];
    const float* Whh1 = (const float*)d_in[6];
    const float* bih1 = (const float*)d_in[7];
    const float* bhh1 = (const float*)d_in[8];
    const float* fcw  = (const float*)d_in[9];
    const float* fcb  = (const float*)d_in[10];
    float* out = (float*)d_out;

    // workspace layout (~161 MB)
    char* ws = (char*)d_ws;
    float* gx        = (float*)ws;     ws += (size_t)32768 * 1024 * 4;  // 134.2 MB
    _Float16* h0f    = (_Float16*)ws;  ws += (size_t)32768 * 256 * 2;   // 16.8 MB
    _Float16* xh     = (_Float16*)ws;  ws += (size_t)32768 * 128 * 2;   // 8.4 MB
    _Float16* hlast  = (_Float16*)ws;  ws += (size_t)64 * 256 * 2;      // 32 KB
    _Float16* Wih0h  = (_Float16*)ws;  ws += (size_t)1024 * 128 * 2;    // 256 KB
    _Float16* Wih1h  = (_Float16*)ws;  ws += (size_t)1024 * 256 * 2;    // 512 KB
    uint4* Wp0       = (uint4*)ws;     ws += (size_t)1024 * 256 * 2;    // 512 KB
    uint4* Wp1       = (uint4*)ws;     ws += (size_t)1024 * 256 * 2;    // 512 KB
    float* bias0     = (float*)ws;     ws += 4096;
    float* bias1     = (float*)ws;     ws += 4096;

    prep_whh<<<128, 256, 0, stream>>>(Whh0, bih0, bhh0, Wp0, bias0);
    prep_whh<<<128, 256, 0, stream>>>(Whh1, bih1, bhh1, Wp1, bias1);
    cvt_f16<<<4096, 256, 0, stream>>>(x, xh, 32768 * 128 / 4);
    cvt_f16<<<128, 256, 0, stream>>>(Wih0, Wih0h, 1024 * 128 / 4);
    cvt_f16<<<256, 256, 0, stream>>>(Wih1, Wih1h, 1024 * 256 / 4);

    // layer 0
    gemm_mfma<<<dim3(512, 16), 256, 0, stream>>>(xh, Wih0h, bias0, gx, 128);
    lstm_scan<<<64, 1024, 0, stream>>>(gx, Wp0, h0f, 1);

    // layer 1
    gemm_mfma<<<dim3(512, 16), 256, 0, stream>>>(h0f, Wih1h, bias1, gx, 256);
    lstm_scan<<<64, 1024, 0, stream>>>(gx, Wp1, hlast, 0);

    fc_softmax<<<64, 64, 0, stream>>>(hlast, fcw, fcb, out);
}

// Round 3
// 1693.365 us; speedup vs baseline: 1.3715x; 1.3715x over previous
//
#include <hip/hip_runtime.h>
#include <cstdint>
#include <cstddef>

// Problem: B=64, T=512, I=128, H=256, 4H=1024, C=3. All fp32 in/out.
typedef _Float16 half2_t __attribute__((ext_vector_type(2)));
typedef _Float16 half8_t __attribute__((ext_vector_type(8)));
typedef float f32x4 __attribute__((ext_vector_type(4)));

static __device__ __forceinline__ float fdot2(half2_t a, half2_t b, float c) {
    return __builtin_amdgcn_fdot2(a, b, c, false);
}
static __device__ __forceinline__ half2_t h2(unsigned int u) {
    return __builtin_bit_cast(half2_t, u);
}
static __device__ __forceinline__ float sigm(float x) {
    return 1.f / (1.f + __expf(-x));
}
static __device__ __forceinline__ float tanh_fast(float x) {
    float ax = fabsf(x);
    float e = __expf(2.f * ax);
    float r = 1.f - 2.f / (e + 1.f);
    return copysignf(r, x);
}

// ---------------------------------------------------------------------------
// prep: W_hh (1024x256 fp32) -> f16 plane layout for the v8 scan.
// plane p = g*16+u (g=gate 0..3, u=k8-sub 0..15), entry idx = q*256+j:
//   Wp[p*512+idx] = 8 halves of W[g*256+j][q*128 + u*8 ..]
// bias = b_ih + b_hh
// ---------------------------------------------------------------------------
__global__ __launch_bounds__(256) void prep_whh(const float* __restrict__ Whh,
                                                const float* __restrict__ bih,
                                                const float* __restrict__ bhh,
                                                uint4* __restrict__ Wp,
                                                float* __restrict__ bias) {
    int n = blockIdx.x * 256 + threadIdx.x;  // 0..32767
    if (n < 1024) bias[n] = bih[n] + bhh[n];
    int p = n >> 9;         // plane 0..63
    int idx = n & 511;      // q*256 + j
    int qq = idx >> 8, jj = idx & 255;
    int g = p >> 4, u = p & 15;
    int row = g * 256 + jj;
    int kb = qq * 128 + u * 8;
    union { uint4 u4; _Float16 h[8]; } cv;
#pragma unroll
    for (int i = 0; i < 8; ++i) cv.h[i] = (_Float16)Whh[row * 256 + kb + i];
    Wp[p * 512 + idx] = cv.u4;
}

// f32 -> f16, 4 elements/thread
__global__ __launch_bounds__(256) void cvt_f16(const float* __restrict__ in,
                                               _Float16* __restrict__ out, int n4) {
    int i = blockIdx.x * 256 + threadIdx.x;
    if (i < n4) {
        float4 v = ((const float4*)in)[i];
        union { ushort4 u; _Float16 h[4]; } cv;
        cv.h[0] = (_Float16)v.x; cv.h[1] = (_Float16)v.y;
        cv.h[2] = (_Float16)v.z; cv.h[3] = (_Float16)v.w;
        ((ushort4*)out)[i] = cv.u;
    }
}

// ---------------------------------------------------------------------------
// gemm_mfma: C[M][1024] = A[M][K](f16) * W[1024][K](f16)^T + bias, fp32 out.
// ---------------------------------------------------------------------------
__global__ __launch_bounds__(256) void gemm_mfma(const _Float16* __restrict__ A,
                                                 const _Float16* __restrict__ Bw,
                                                 const float* __restrict__ bias,
                                                 float* __restrict__ Cmat, int K) {
    __shared__ _Float16 As[64][72];
    __shared__ _Float16 Bs[64][72];
    const int tid = threadIdx.x;
    const int wave = tid >> 6, lane = tid & 63;
    const int quad = lane >> 4, l16 = lane & 15;
    const int m0 = blockIdx.x * 64, n0 = blockIdx.y * 64;
    const int sr = tid >> 2;
    const int sc = (tid & 3) * 16;

    f32x4 acc[4] = {};

    for (int k0 = 0; k0 < K; k0 += 64) {
        const uint4 a0v = *(const uint4*)(A + (size_t)(m0 + sr) * K + k0 + sc);
        const uint4 a1v = *(const uint4*)(A + (size_t)(m0 + sr) * K + k0 + sc + 8);
        const uint4 b0v = *(const uint4*)(Bw + (size_t)(n0 + sr) * K + k0 + sc);
        const uint4 b1v = *(const uint4*)(Bw + (size_t)(n0 + sr) * K + k0 + sc + 8);
        __syncthreads();
        *(uint4*)&As[sr][sc] = a0v;
        *(uint4*)&As[sr][sc + 8] = a1v;
        *(uint4*)&Bs[sr][sc] = b0v;
        *(uint4*)&Bs[sr][sc + 8] = b1v;
        __syncthreads();
#pragma unroll
        for (int kc = 0; kc < 64; kc += 32) {
            half8_t af = *(const half8_t*)&As[wave * 16 + l16][kc + quad * 8];
#pragma unroll
            for (int nb = 0; nb < 4; ++nb) {
                half8_t bf = *(const half8_t*)&Bs[nb * 16 + l16][kc + quad * 8];
                acc[nb] = __builtin_amdgcn_mfma_f32_16x16x32_f16(af, bf, acc[nb], 0, 0, 0);
            }
        }
    }
#pragma unroll
    for (int nb = 0; nb < 4; ++nb) {
#pragma unroll
        for (int i = 0; i < 4; ++i) {
            int row = m0 + wave * 16 + quad * 4 + i;
            int col = n0 + nb * 16 + l16;
            Cmat[(size_t)row * 1024 + col] = acc[nb][i] + bias[col];
        }
    }
}

// ---------------------------------------------------------------------------
// lstm_scan v8: 64 WGs x 512 thr (8 waves = 2 waves/SIMD -> 256-VGPR budget).
// Thread tid = q*256+j computes the 4 gate partials of unit j over K-half
// [q*128, q*128+128). Weights: 48 uint4 (192 VGPRs) persistent in registers
// (gates i,f,g), 16 planes (128 KB LDS) for gate o.
// h-reads are WAVE-UNIFORM (q is constant per wave) -> broadcast-cheap LDS.
// Gate-partial exchange via 8 KB pex (1 b128 write + 2 b128 reads per unit);
// 256 updater threads do activations + c,h. 2 barriers/step.
// LDS-op budget/step: ~128 per-lane b128 (weights) + ~128 uniform (h) +
// ~30 exchange ops -- vs v7's ~420 per-lane ops. 
// ---------------------------------------------------------------------------
__global__ __launch_bounds__(512, 2)
void lstm_scan(const float* __restrict__ gx,
               const uint4* __restrict__ Wp,
               _Float16* __restrict__ h_out,
               int store_all) {
    const int b = blockIdx.x;
    const int tid = threadIdx.x;   // = q*256 + j
    const int q = tid >> 8;        // K-half 0/1 (wave-uniform: waves 0-3 q=0)
    const int j = tid & 255;       // hidden unit

    __shared__ uint4 wlds[16 * 512];                                 // 128 KB (gate o)
    __shared__ f32x4 pex[512] __attribute__((aligned(16)));          // 8 KB
    __shared__ _Float16 hbuf[2][256] __attribute__((aligned(16)));   // 1 KB
    __shared__ _Float16 hist[8][256] __attribute__((aligned(16)));   // 4 KB

    // stage gate-o planes into LDS
#pragma unroll
    for (int p = 0; p < 16; ++p) wlds[p * 512 + tid] = Wp[(48 + p) * 512 + tid];
    // persistent register weights: gates i,f,g (planes 0..47, 192 VGPRs)
    uint4 wreg[48];
#pragma unroll
    for (int p = 0; p < 48; ++p) wreg[p] = Wp[p * 512 + tid];

    if (tid < 256) hbuf[0][tid] = (_Float16)0.f;
    float c = 0.f;
    // this thread folds gx rows {2q*256+j, (2q+1)*256+j} into its partials
    const float* gxb = gx + (size_t)b * 512 * 1024 + (size_t)(q * 512 + j);
    float gA = gxb[0], gB = gxb[256];
    __syncthreads();  // wlds + hbuf[0] visible

    for (int t = 0; t < 512; ++t) {
        // prefetch next step's gx
        float gA_n = 0.f, gB_n = 0.f;
        if (t < 511) {
            gA_n = gxb[(size_t)(t + 1) * 1024];
            gB_n = gxb[(size_t)(t + 1) * 1024 + 256];
        }

        // wave-uniform h K-half: 16 uint4 broadcast reads
        const char* hp = (const char*)&hbuf[t & 1][0] + q * 256;
        float a0 = 0.f, a1 = 0.f, a2 = 0.f, a3 = 0.f;
#pragma unroll
        for (int u = 0; u < 16; ++u) {
            const uint4 hv = *(const uint4*)(hp + u * 16);
            const uint4 w0 = wreg[u];
            const uint4 w1 = wreg[16 + u];
            const uint4 w2 = wreg[32 + u];
            const uint4 w3 = wlds[u * 512 + tid];
            a0 = fdot2(h2(w0.x), h2(hv.x), a0);
            a1 = fdot2(h2(w1.x), h2(hv.x), a1);
            a2 = fdot2(h2(w2.x), h2(hv.x), a2);
            a3 = fdot2(h2(w3.x), h2(hv.x), a3);
            a0 = fdot2(h2(w0.y), h2(hv.y), a0);
            a1 = fdot2(h2(w1.y), h2(hv.y), a1);
            a2 = fdot2(h2(w2.y), h2(hv.y), a2);
            a3 = fdot2(h2(w3.y), h2(hv.y), a3);
            a0 = fdot2(h2(w0.z), h2(hv.z), a0);
            a1 = fdot2(h2(w1.z), h2(hv.z), a1);
            a2 = fdot2(h2(w2.z), h2(hv.z), a2);
            a3 = fdot2(h2(w3.z), h2(hv.z), a3);
            a0 = fdot2(h2(w0.w), h2(hv.w), a0);
            a1 = fdot2(h2(w1.w), h2(hv.w), a1);
            a2 = fdot2(h2(w2.w), h2(hv.w), a2);
            a3 = fdot2(h2(w3.w), h2(hv.w), a3);
        }
        // fold gx once per gate row (q=0 folds gates i,f; q=1 folds g,o)
        if (q == 0) { a0 += gA; a1 += gB; }
        else        { a2 += gA; a3 += gB; }

        f32x4 pv = {a0, a1, a2, a3};
        pex[tid] = pv;
        gA = gA_n; gB = gB_n;
        __syncthreads();  // barrier1: pex visible; all hbuf[t&1] reads done

        if (tid < 256) {
            const f32x4 v0 = pex[tid];        // q=0 partials for unit tid
            const f32x4 v1 = pex[256 + tid];  // q=1 partials
            const float ai = v0[0] + v1[0];
            const float af = v0[1] + v1[1];
            const float ag = v0[2] + v1[2];
            const float ao = v0[3] + v1[3];
            const float iv = sigm(ai);
            const float fv = sigm(af);
            const float gv = tanh_fast(ag);
            const float ov = sigm(ao);
            c = fv * c + iv * gv;
            const _Float16 hh = (_Float16)(ov * tanh_fast(c));
            hbuf[(t + 1) & 1][tid] = hh;
            if (store_all) hist[t & 7][tid] = hh;
        }
        __syncthreads();  // barrier2: new h + hist visible

        if (store_all && (t & 7) == 7) {
            // flush 8 steps (4 KB) with all 512 threads (8 B each)
            const uint2 v = ((const uint2*)hist)[tid];
            *(uint2*)(h_out + (size_t)b * 512 * 256 + (size_t)(t - 7) * 256 + tid * 4) = v;
        }
    }
    if (!store_all && tid < 256) {
        // final h lives in hbuf[0] (512 & 1 == 0)
        h_out[(size_t)b * 256 + tid] = hbuf[0][tid];
    }
}

// ---------------------------------------------------------------------------
// fc_softmax: logits = hlast[b,:](f16) @ fc_w^T + fc_b, softmax over 3
// ---------------------------------------------------------------------------
__global__ __launch_bounds__(64) void fc_softmax(const _Float16* __restrict__ hlast,
                                                 const float* __restrict__ fcw,
                                                 const float* __restrict__ fcb,
                                                 float* __restrict__ out) {
    const int b = blockIdx.x;
    const int lane = threadIdx.x;
    const _Float16* h = hlast + (size_t)b * 256;
    float p0 = 0.f, p1 = 0.f, p2 = 0.f;
    for (int k = lane; k < 256; k += 64) {
        float hv = (float)h[k];
        p0 += hv * fcw[k];
        p1 += hv * fcw[256 + k];
        p2 += hv * fcw[512 + k];
    }
#pragma unroll
    for (int off = 32; off > 0; off >>= 1) {
        p0 += __shfl_down(p0, off);
        p1 += __shfl_down(p1, off);
        p2 += __shfl_down(p2, off);
    }
    if (lane == 0) {
        float l0 = p0 + fcb[0], l1 = p1 + fcb[1], l2 = p2 + fcb[2];
        float m = fmaxf(l0, fmaxf(l1, l2));
        float e0 = __expf(l0 - m), e1 = __expf(l1 - m), e2 = __expf(l2 - m);
        float s = 1.f / (e0 + e1 + e2);
        out[b * 3 + 0] = e0 * s;
        out[b * 3 + 1] = e1 * s;
        out[b * 3 + 2] = e2 * s;
    }
}

extern "C" void kernel_launch(void* const* d_in, const int* in_sizes, int n_in,
                              void* d_out, int out_size, void* d_ws, size_t ws_size,
                              hipStream_t stream) {
    const float* x    = (const float*)d_in[0];
    const float* Wih0 = (const float*)d_in[1];
    const float* Whh0 = (const float*)d_in[2];
    const float* bih0 = (const float*)d_in[3];
    const float* bhh0 = (const float*)d_in[4];
    const float* Wih1 = (const float*)d_in[5];
    const float* Whh1 = (const float*)d_in[6];
    const float* bih1 = (const float*)d_in[7];
    const float* bhh1 = (const float*)d_in[8];
    const float* fcw  = (const float*)d_in[9];
    const float* fcb  = (const float*)d_in[10];
    float* out = (float*)d_out;

    // workspace layout (~161 MB)
    char* ws = (char*)d_ws;
    float* gx        = (float*)ws;     ws += (size_t)32768 * 1024 * 4;  // 134.2 MB
    _Float16* h0f    = (_Float16*)ws;  ws += (size_t)32768 * 256 * 2;   // 16.8 MB
    _Float16* xh     = (_Float16*)ws;  ws += (size_t)32768 * 128 * 2;   // 8.4 MB
    _Float16* hlast  = (_Float16*)ws;  ws += (size_t)64 * 256 * 2;      // 32 KB
    _Float16* Wih0h  = (_Float16*)ws;  ws += (size_t)1024 * 128 * 2;    // 256 KB
    _Float16* Wih1h  = (_Float16*)ws;  ws += (size_t)1024 * 256 * 2;    // 512 KB
    uint4* Wp0       = (uint4*)ws;     ws += (size_t)1024 * 256 * 2;    // 512 KB
    uint4* Wp1       = (uint4*)ws;     ws += (size_t)1024 * 256 * 2;    // 512 KB
    float* bias0     = (float*)ws;     ws += 4096;
    float* bias1     = (float*)ws;     ws += 4096;

    prep_whh<<<128, 256, 0, stream>>>(Whh0, bih0, bhh0, Wp0, bias0);
    prep_whh<<<128, 256, 0, stream>>>(Whh1, bih1, bhh1, Wp1, bias1);
    cvt_f16<<<4096, 256, 0, stream>>>(x, xh, 32768 * 128 / 4);
    cvt_f16<<<128, 256, 0, stream>>>(Wih0, Wih0h, 1024 * 128 / 4);
    cvt_f16<<<256, 256, 0, stream>>>(Wih1, Wih1h, 1024 * 256 / 4);

    // layer 0
    gemm_mfma<<<dim3(512, 16), 256, 0, stream>>>(xh, Wih0h, bias0, gx, 128);
    lstm_scan<<<64, 512, 0, stream>>>(gx, Wp0, h0f, 1);

    // layer 1
    gemm_mfma<<<dim3(512, 16), 256, 0, stream>>>(h0f, Wih1h, bias1, gx, 256);
    lstm_scan<<<64, 512, 0, stream>>>(gx, Wp1, hlast, 0);

    fc_softmax<<<64, 64, 0, stream>>>(hlast, fcw, fcb, out);
}